// Round 14
// baseline (99.739 us; speedup 1.0000x reference)
//
#include <hip/hip_runtime.h>

#define EPS_F 1e-8f
#define BLOCK 256
#define MAXG  1280                  // 5 blocks/CU co-resident (LDS 140 KB/CU)
#define SLAB_CH 896                 // 16B chunks per slab (256 elem × 14 dw / 4)
#define SLAB_DW (SLAB_CH * 4)       // 3584 dwords per slab

typedef float vf4 __attribute__((ext_vector_type(4)));

typedef const __attribute__((address_space(1))) void* gptr_t;
typedef __attribute__((address_space(3))) void* sptr_t;

__device__ __forceinline__ float fast_rcp(float x) {
    return __builtin_amdgcn_rcpf(x);
}
// HW sincos in revolutions; |yaw| < ~4.5 rad so fract-reduction suffices.
__device__ __forceinline__ void fast_sincos(float x, float* s, float* c) {
    float t = x * 0.15915494309189535f;
    t = __builtin_amdgcn_fractf(t);
    *s = __builtin_amdgcn_sinf(t);
    *c = __builtin_amdgcn_cosf(t);
}

// Edge contribution to 2*signed-Area(P ∩ [-W,W]x[-H,H]); boundary integral
// of h(y)=clamp(y,-H,H)+H over the edge clipped to the x-slab. rdx/rdy
// shareable between parallel edges (sign flips cancel in min/max).
__device__ __forceinline__ float edge_contrib(float ax, float ay,
                                              float dx, float dy,
                                              float rdx, float rdy,
                                              float W, float H) {
    float tA = (-W - ax) * rdx;
    float tB = ( W - ax) * rdx;
    float ta = fmaxf(fminf(tA, tB), 0.f);
    float tb = fminf(fmaxf(tA, tB), 1.f);
    tb = fmaxf(ta, tb);

    float u0 = (-H - ay) * rdy;
    float u1 = ( H - ay) * rdy;
    float tm0 = fminf(u0, u1), tm1 = fmaxf(u0, u1);
    float t1 = fminf(fmaxf(tm0, ta), tb);
    float t2 = fminf(fmaxf(tm1, ta), tb);

    float x0 = fmaf(ta, dx, ax), y0 = fmaf(ta, dy, ay);
    float x1 = fmaf(t1, dx, ax), y1 = fmaf(t1, dy, ay);
    float x2 = fmaf(t2, dx, ax), y2 = fmaf(t2, dy, ay);
    float x3 = fmaf(tb, dx, ax), y3 = fmaf(tb, dy, ay);
    float h0 = fminf(fmaxf(y0, -H), H) + H;
    float h1 = fminf(fmaxf(y1, -H), H) + H;
    float h2 = fminf(fmaxf(y2, -H), H) + H;
    float h3 = fminf(fmaxf(y3, -H), H) + H;

    return (x1 - x0) * (h0 + h1) + (x2 - x1) * (h1 + h2) + (x3 - x2) * (h2 + h3);
}

// Per-element IoU loss; p/q point at 7-float records in LDS.
__device__ __forceinline__ float elem_loss(const float* p, const float* q,
                                           float wgt) {
    float a0=p[0],a1=p[1],a2=p[2],a3=p[3],a4=p[4],a5=p[5],a6=p[6];
    float b0=q[0],b1=q[1],b2=q[2],b3=q[3],b4=q[4],b5=q[5],b6=q[6];

    float s1, c1, sd, cd;
    fast_sincos(a6, &s1, &c1);
    fast_sincos(b6 - a6, &sd, &cd);
    float dxc = b0 - a0, dyc = b1 - a1;
    float tx =  c1 * dxc + s1 * dyc;
    float ty = -s1 * dxc + c1 * dyc;
    float W = 0.5f * a3, H = 0.5f * a4;
    float w2 = 0.5f * b3, h2 = 0.5f * b4;

    float cw = cd * w2, sw = sd * w2, ch = cd * h2, sh = sd * h2;
    float q0x =  cw - sh + tx, q0y =  sw + ch + ty;
    float q1x = -cw - sh + tx, q1y = -sw + ch + ty;
    float q2x = -cw + sh + tx, q2y = -sw - ch + ty;
    float q3x =  cw + sh + tx, q3y =  sw - ch + ty;

    float e0x = -2.f * cw, e0y = -2.f * sw;   // q1-q0
    float e1x =  2.f * sh, e1y = -2.f * ch;   // q2-q1
    float g0x = (fabsf(e0x) < 1e-20f) ? 1e-20f : e0x;
    float g0y = (fabsf(e0y) < 1e-20f) ? 1e-20f : e0y;
    float g1x = (fabsf(e1x) < 1e-20f) ? 1e-20f : e1x;
    float g1y = (fabsf(e1y) < 1e-20f) ? 1e-20f : e1y;
    float r0x = fast_rcp(g0x), r0y = fast_rcp(g0y);
    float r1x = fast_rcp(g1x), r1y = fast_rcp(g1y);

    float s = edge_contrib(q0x, q0y,  e0x,  e0y,  r0x,  r0y, W, H)
            + edge_contrib(q1x, q1y,  e1x,  e1y,  r1x,  r1y, W, H)
            + edge_contrib(q2x, q2y, -e0x, -e0y, -r0x, -r0y, W, H)
            + edge_contrib(q3x, q3y, -e1x, -e1y, -r1x, -r1y, W, H);
    float area = 0.5f * fabsf(s);

    float zmax = fminf(a2 + 0.5f * a5, b2 + 0.5f * b5);
    float zmin = fmaxf(a2 - 0.5f * a5, b2 - 0.5f * b5);
    float inter3d = area * fmaxf(zmax - zmin, 0.f);
    float v1 = a3 * a4 * a5;
    float v2 = b3 * b4 * b5;
    float iou = inter3d * fast_rcp(v1 + v2 - inter3d + EPS_F);
    return (1.f - iou) * wgt;
}

// Double-buffered LDS pipeline with async global->LDS DMA (width=16).
// Any-N safe: DMA src clamped per-lane to the last valid 16B (finite
// garbage), OOB elements killed by wgt=0. 5 blocks/CU co-resident
// (launch_bounds(256,5) caps VGPR ~102; LDS 28KB x 5 = 140KB < 160KB).
__global__ __launch_bounds__(BLOCK, 5) void iou3d_partial_dma(
    const float* __restrict__ pred, const float* __restrict__ target,
    const float* __restrict__ weight, float* __restrict__ partials,
    int N, int stride_e, int iters)
{
    __shared__ vf4 lds4[2 * SLAB_CH];            // 28 KB
    const int tid = threadIdx.x;
    const long maxdw = 7L * N - 4;               // last valid 16B chunk start

    auto stage = [&](int it, int buf) {
        long g0 = ((long)blockIdx.x * BLOCK + (long)it * stride_e) * 7;
        #pragma unroll
        for (int k = 0; k < 3; ++k) {
            int c = k * BLOCK + tid;             // source uniform per wave
            long g = (c < 448) ? g0 + 4L * c : g0 + 4L * c - SLAB_DW / 2;
            g = (g > maxdw) ? maxdw : g;
            const float* src = ((c < 448) ? pred : target) + g;
            __builtin_amdgcn_global_load_lds((gptr_t)src,
                                             (sptr_t)&lds4[buf * SLAB_CH + c],
                                             16, 0, 0);
        }
        if (tid < 128) {                         // waves 0,1: c = 768..895
            int c = 3 * BLOCK + tid;
            long g = g0 + 4L * c - SLAB_DW / 2;
            g = (g > maxdw) ? maxdw : g;
            __builtin_amdgcn_global_load_lds((gptr_t)(target + g),
                                             (sptr_t)&lds4[buf * SLAB_CH + c],
                                             16, 0, 0);
        }
    };

    stage(0, 0);
    int i0 = blockIdx.x * BLOCK + tid;
    float wcur = (i0 < N) ? weight[i0] : 0.f;
    __syncthreads();

    float val = 0.f;
    #pragma unroll 1
    for (int it = 0; it < iters; ++it) {
        bool more = (it + 1 < iters);
        if (more) stage(it + 1, (it + 1) & 1);   // fire-and-forget DMA
        float wnext = 0.f;
        if (more) {
            int inx = i0 + (it + 1) * stride_e;
            wnext = (inx < N) ? weight[(inx < N) ? inx : 0] : 0.f;
        }

        const float* base = (const float*)lds4 + (size_t)(it & 1) * SLAB_DW;
        val += elem_loss(base + 7 * tid, base + SLAB_DW / 2 + 7 * tid, wcur);

        wcur = wnext;
        __syncthreads();                         // drains DMA (vmcnt) + barrier
    }

    #pragma unroll
    for (int off = 32; off > 0; off >>= 1) val += __shfl_down(val, off, 64);
    __shared__ float wsum[4];
    int lane = tid & 63, wid = tid >> 6;
    if (lane == 0) wsum[wid] = val;
    __syncthreads();
    if (tid == 0)
        partials[blockIdx.x] = wsum[0] + wsum[1] + wsum[2] + wsum[3];
}

__global__ __launch_bounds__(BLOCK) void reduce_partials_kernel(
    const float* __restrict__ partials, float* __restrict__ out,
    int nparts, float invN)
{
    float v = 0.f;
    for (int k = threadIdx.x; k < nparts; k += BLOCK) v += partials[k];
    #pragma unroll
    for (int off = 32; off > 0; off >>= 1) v += __shfl_down(v, off, 64);
    __shared__ float wsum[4];
    int lane = threadIdx.x & 63, wid = threadIdx.x >> 6;
    if (lane == 0) wsum[wid] = v;
    __syncthreads();
    if (threadIdx.x == 0)
        out[0] = (wsum[0] + wsum[1] + wsum[2] + wsum[3]) * invN;
}

extern "C" void kernel_launch(void* const* d_in, const int* in_sizes, int n_in,
                              void* d_out, int out_size, void* d_ws, size_t ws_size,
                              hipStream_t stream) {
    const float* pred   = (const float*)d_in[0];
    const float* target = (const float*)d_in[1];
    const float* weight = (const float*)d_in[2];
    float* out = (float*)d_out;
    float* partials = (float*)d_ws;
    int N = in_sizes[2];

    int nblocks = (N + BLOCK - 1) / BLOCK;
    int grid = (nblocks < MAXG) ? nblocks : MAXG;
    int stride_e = grid * BLOCK;
    int iters = (N + stride_e - 1) / stride_e;   // 4 for N = 2^20 (last partial)

    iou3d_partial_dma<<<grid, BLOCK, 0, stream>>>(pred, target, weight,
                                                  partials, N, stride_e, iters);
    reduce_partials_kernel<<<1, BLOCK, 0, stream>>>(partials, out, grid,
                                                    1.f / (float)N);
}